// Round 1
// baseline (69.111 us; speedup 1.0000x reference)
//
#include <hip/hip_runtime.h>

static constexpr int NB = 4;    // batch
static constexpr int L  = 256;  // Lx == Lm
static constexpr int D  = 256;

__device__ __forceinline__ float fast_rcp(float x) {
#if __has_builtin(__builtin_amdgcn_rcpf)
    return __builtin_amdgcn_rcpf(x);
#else
    return 1.0f / x;
#endif
}

__device__ __forceinline__ float fast_exp(float x) {
#if __has_builtin(__builtin_amdgcn_exp2f)
    return __builtin_amdgcn_exp2f(x * 1.4426950408889634f);
#else
    return __expf(x);
#endif
}

// tanh(y) = 1 - 2/(exp(2y)+1);  exp(2y) = exp2(y * 2*log2(e))
__device__ __forceinline__ float tanh_fast(float y) {
#if __has_builtin(__builtin_amdgcn_exp2f)
    float e = __builtin_amdgcn_exp2f(y * 2.8853900817779268f);
#else
    float e = __expf(2.0f * y);
#endif
    return fmaf(-2.0f, fast_rcp(e + 1.0f), 1.0f);
}

// ---------------------------------------------------------------------------
// Kernel 1: i1 = x @ W1^T + b1   (blocks [0, nblk));  i2 = mem @ W2^T  (rest)
// Each block: ROWS rows staged in LDS, thread t owns output column t.
// ---------------------------------------------------------------------------
template<int ROWS>
__global__ __launch_bounds__(256) void linear_kernel(
    const float* __restrict__ x, const float* __restrict__ mem,
    const float* __restrict__ w1, const float* __restrict__ b1,
    const float* __restrict__ w2,
    float* __restrict__ i1, float* __restrict__ i2)
{
    const int nblk  = (NB * L) / ROWS;
    const int which = blockIdx.x / nblk;          // 0: item1, 1: item2
    const int rb    = (blockIdx.x % nblk) * ROWS; // first global row
    const int t     = threadIdx.x;

    const float* src = which ? mem : x;
    const float* W   = which ? w2  : w1;
    float*       dst = which ? i2  : i1;

    __shared__ __align__(16) float xs[ROWS * D];
    float4* xs4 = reinterpret_cast<float4*>(xs);
    const float4* src4 = reinterpret_cast<const float4*>(src);
    const int nf4 = ROWS * (D / 4);
    for (int idx = t; idx < nf4; idx += 256)
        xs4[idx] = src4[rb * (D / 4) + idx];
    __syncthreads();

    const float4* W4 = reinterpret_cast<const float4*>(W) + t * (D / 4);
    float acc[ROWS];
#pragma unroll
    for (int r = 0; r < ROWS; ++r) acc[r] = 0.0f;

    for (int d4 = 0; d4 < D / 4; ++d4) {
        float4 w = W4[d4];
#pragma unroll
        for (int r = 0; r < ROWS; ++r) {
            float4 xv = xs4[r * (D / 4) + d4];   // broadcast across lanes
            acc[r] = fmaf(xv.x, w.x, acc[r]);
            acc[r] = fmaf(xv.y, w.y, acc[r]);
            acc[r] = fmaf(xv.z, w.z, acc[r]);
            acc[r] = fmaf(xv.w, w.w, acc[r]);
        }
    }
    const float bias = which ? 0.0f : b1[t];
#pragma unroll
    for (int r = 0; r < ROWS; ++r)
        dst[(rb + r) * D + t] = acc[r] + bias;
}

// ---------------------------------------------------------------------------
// Kernel 2: S[b,x,m] = sum_d tanh(i1[b,x,d] + i2[b,m,d]) * wst[d]
// 16x16 (x,m) tile per block; writes masked S to outS, unmasked S^T to ST.
// ---------------------------------------------------------------------------
__global__ __launch_bounds__(256) void score_kernel(
    const float* __restrict__ i1, const float* __restrict__ i2,
    const float* __restrict__ wst, const int* __restrict__ mask,
    float* __restrict__ outS, float* __restrict__ ST)
{
    const int bid = blockIdx.x;
    const int b   = bid >> 8;
    const int xt  = ((bid >> 4) & 15) * 16;
    const int mt  = (bid & 15) * 16;
    const int t   = threadIdx.x;

    constexpr int PAD = 260;          // floats per LDS row (2-way conflicts only)
    __shared__ __align__(16) float s1[16 * PAD];
    __shared__ __align__(16) float s2[16 * PAD];
    __shared__ __align__(16) float sw[D];
    __shared__ float stile[16 * 17];

    const float4* i14 = reinterpret_cast<const float4*>(i1) + (b * L + xt) * (D / 4);
    const float4* i24 = reinterpret_cast<const float4*>(i2) + (b * L + mt) * (D / 4);
    float4* s14 = reinterpret_cast<float4*>(s1);
    float4* s24 = reinterpret_cast<float4*>(s2);
#pragma unroll
    for (int k = 0; k < 4; ++k) {
        int idx = k * 256 + t;
        int r = idx >> 6, c = idx & 63;
        s14[r * (PAD / 4) + c] = i14[r * (D / 4) + c];
        s24[r * (PAD / 4) + c] = i24[r * (D / 4) + c];
    }
    sw[t] = wst[t];
    __syncthreads();

    const int xl = t >> 4, ml = t & 15;
    const float4* a4 = s14 + xl * (PAD / 4);
    const float4* b4 = s24 + ml * (PAD / 4);
    const float4* w4 = reinterpret_cast<const float4*>(sw);
    float acc = 0.0f;
    for (int d4 = 0; d4 < D / 4; ++d4) {
        float4 a  = a4[d4];
        float4 bb = b4[d4];
        float4 w  = w4[d4];
        acc = fmaf(tanh_fast(a.x + bb.x), w.x, acc);
        acc = fmaf(tanh_fast(a.y + bb.y), w.y, acc);
        acc = fmaf(tanh_fast(a.z + bb.z), w.z, acc);
        acc = fmaf(tanh_fast(a.w + bb.w), w.w, acc);
    }
    const int xi = xt + xl, mi = mt + ml;
    outS[((b * L + xi) << 8) + mi] = (mask[b * L + mi] == 0) ? -1e30f : acc;

    stile[ml * 17 + xl] = acc;        // transpose tile in LDS
    __syncthreads();
    const int m2 = t >> 4, x2 = t & 15;
    ST[((b * L + mt + m2) << 8) + xt + x2] = stile[m2 * 17 + x2];
}

// ---------------------------------------------------------------------------
// Kernel 3: out[row,:] = softmax(S[row,:]) @ V[b]   for R rows per block
// ---------------------------------------------------------------------------
template<int R>
__global__ __launch_bounds__(256) void attn_kernel(
    const float* __restrict__ S, const float* __restrict__ V,
    float* __restrict__ out)
{
    const int row0 = blockIdx.x * R;
    const int b    = row0 >> 8;     // R divides 256 -> whole block same batch
    const int t    = threadIdx.x;

    __shared__ float p[R][L];
    __shared__ float red[8];
    __shared__ __align__(16) float4 part[R][4][64];

#pragma unroll
    for (int r = 0; r < R; ++r) {
        float sv = S[((row0 + r) << 8) + t];
        float m = sv;
#pragma unroll
        for (int o = 32; o; o >>= 1) m = fmaxf(m, __shfl_xor(m, o));
        if ((t & 63) == 0) red[t >> 6] = m;
        __syncthreads();
        m = fmaxf(fmaxf(red[0], red[1]), fmaxf(red[2], red[3]));
        float e = fast_exp(sv - m);
        float s = e;
#pragma unroll
        for (int o = 32; o; o >>= 1) s += __shfl_xor(s, o);
        if ((t & 63) == 0) red[4 + (t >> 6)] = s;
        __syncthreads();
        s = red[4] + red[5] + red[6] + red[7];
        p[r][t] = e / s;
    }
    __syncthreads();

    const int d4 = t & 63, q = t >> 6;
    const float4* V4 = reinterpret_cast<const float4*>(V) + (b * L) * (D / 4);
    float4 acc[R];
#pragma unroll
    for (int r = 0; r < R; ++r) acc[r] = make_float4(0.f, 0.f, 0.f, 0.f);

    for (int mm = q * 64; mm < (q + 1) * 64; ++mm) {
        float4 v = V4[mm * (D / 4) + d4];
#pragma unroll
        for (int r = 0; r < R; ++r) {
            float pm = p[r][mm];
            acc[r].x = fmaf(pm, v.x, acc[r].x);
            acc[r].y = fmaf(pm, v.y, acc[r].y);
            acc[r].z = fmaf(pm, v.z, acc[r].z);
            acc[r].w = fmaf(pm, v.w, acc[r].w);
        }
    }
#pragma unroll
    for (int r = 0; r < R; ++r) part[r][q][d4] = acc[r];
    __syncthreads();

    if (t < 64) {
#pragma unroll
        for (int r = 0; r < R; ++r) {
            float4 r0 = part[r][0][t], r1 = part[r][1][t];
            float4 r2 = part[r][2][t], r3 = part[r][3][t];
            float4 o;
            o.x = (r0.x + r1.x) + (r2.x + r3.x);
            o.y = (r0.y + r1.y) + (r2.y + r3.y);
            o.z = (r0.z + r1.z) + (r2.z + r3.z);
            o.w = (r0.w + r1.w) + (r2.w + r3.w);
            reinterpret_cast<float4*>(out)[((row0 + r) << 6) + t] = o;
        }
    }
}

extern "C" void kernel_launch(void* const* d_in, const int* in_sizes, int n_in,
                              void* d_out, int out_size, void* d_ws, size_t ws_size,
                              hipStream_t stream)
{
    const float* x    = (const float*)d_in[0];  // [4,256,256]
    const float* mem  = (const float*)d_in[1];  // [4,256,256]
    const int*   mask = (const int*)  d_in[2];  // [4,256]
    const float* w1   = (const float*)d_in[3];  // [256,256]
    const float* b1   = (const float*)d_in[4];  // [256]
    const float* w2   = (const float*)d_in[5];  // [256,256]
    const float* wst  = (const float*)d_in[6];  // [256]

    float* out   = (float*)d_out;               // [4,256,256]
    float* Smask = out + NB * L * L;            // [4,256,256] (masked S, output 1)
    float* agg   = Smask + NB * L * L;          // [4,256,256] (agg_2_h, output 2)

    float* i1 = (float*)d_ws;                   // [4,256,256]
    float* i2 = i1 + NB * L * D;                // [4,256,256]
    float* ST = i2 + NB * L * D;                // [4,256,256] unmasked S^T

    constexpr int ROWS = 8;
    linear_kernel<ROWS><<<2 * (NB * L / ROWS), 256, 0, stream>>>(x, mem, w1, b1, w2, i1, i2);
    score_kernel<<<NB * (L / 16) * (L / 16), 256, 0, stream>>>(i1, i2, wst, mask, Smask, ST);
    attn_kernel<4><<<NB * L / 4, 256, 0, stream>>>(Smask, mem, out);  // out
    attn_kernel<4><<<NB * L / 4, 256, 0, stream>>>(ST, x, agg);       // agg_2_h
}

// Round 2
// 50.017 us; speedup vs baseline: 1.3817x; 1.3817x over previous
//
#include <hip/hip_runtime.h>

static constexpr int NB = 4;    // batch
static constexpr int L  = 256;  // Lx == Lm
static constexpr int D  = 256;

__device__ __forceinline__ float fast_rcp(float x) {
#if __has_builtin(__builtin_amdgcn_rcpf)
    return __builtin_amdgcn_rcpf(x);
#else
    return 1.0f / x;
#endif
}

__device__ __forceinline__ float fast_exp(float x) {
#if __has_builtin(__builtin_amdgcn_exp2f)
    return __builtin_amdgcn_exp2f(x * 1.4426950408889634f);
#else
    return __expf(x);
#endif
}

// tanh(y) = 1 - 2/(exp(2y)+1);  exp(2y) = exp2(y * 2*log2(e))
__device__ __forceinline__ float tanh_fast(float y) {
#if __has_builtin(__builtin_amdgcn_exp2f)
    float e = __builtin_amdgcn_exp2f(y * 2.8853900817779268f);
#else
    float e = __expf(2.0f * y);
#endif
    return fmaf(-2.0f, fast_rcp(e + 1.0f), 1.0f);
}

// ---------------------------------------------------------------------------
// Kernel 1: i1 = x @ W1^T + b1   (blocks [0, nblk));  i2 = mem @ W2^T  (rest)
// ROWS=4 -> 512 blocks = 2 waves/SIMD for latency hiding.
// ---------------------------------------------------------------------------
template<int ROWS>
__global__ __launch_bounds__(256) void linear_kernel(
    const float* __restrict__ x, const float* __restrict__ mem,
    const float* __restrict__ w1, const float* __restrict__ b1,
    const float* __restrict__ w2,
    float* __restrict__ i1, float* __restrict__ i2)
{
    const int nblk  = (NB * L) / ROWS;
    const int which = blockIdx.x / nblk;          // 0: item1, 1: item2
    const int rb    = (blockIdx.x % nblk) * ROWS; // first global row
    const int t     = threadIdx.x;

    const float* src = which ? mem : x;
    const float* W   = which ? w2  : w1;
    float*       dst = which ? i2  : i1;

    __shared__ __align__(16) float xs[ROWS * D];
    float4* xs4 = reinterpret_cast<float4*>(xs);
    const float4* src4 = reinterpret_cast<const float4*>(src);
    const int nf4 = ROWS * (D / 4);               // 256 with ROWS=4
    for (int idx = t; idx < nf4; idx += 256)
        xs4[idx] = src4[rb * (D / 4) + idx];
    __syncthreads();

    const float4* W4 = reinterpret_cast<const float4*>(W) + t * (D / 4);
    float acc[ROWS];
#pragma unroll
    for (int r = 0; r < ROWS; ++r) acc[r] = 0.0f;

#pragma unroll 8
    for (int d4 = 0; d4 < D / 4; ++d4) {
        float4 w = W4[d4];
#pragma unroll
        for (int r = 0; r < ROWS; ++r) {
            float4 xv = xs4[r * (D / 4) + d4];   // LDS broadcast (free)
            acc[r] = fmaf(xv.x, w.x, acc[r]);
            acc[r] = fmaf(xv.y, w.y, acc[r]);
            acc[r] = fmaf(xv.z, w.z, acc[r]);
            acc[r] = fmaf(xv.w, w.w, acc[r]);
        }
    }
    const float bias = which ? 0.0f : b1[t];
#pragma unroll
    for (int r = 0; r < ROWS; ++r)
        dst[(rb + r) * D + t] = acc[r] + bias;
}

// ---------------------------------------------------------------------------
// Kernel 2: S[b,x,m] = sum_d tanh(i1[b,x,d] + i2[b,m,d]) * wst[d]
// 16x16 (x,m) tile per block; writes masked S to outS, unmasked S^T to ST.
// wst read with uniform index -> scalar loads (no LDS traffic for w).
// ---------------------------------------------------------------------------
__global__ __launch_bounds__(256) void score_kernel(
    const float* __restrict__ i1, const float* __restrict__ i2,
    const float* __restrict__ wst, const int* __restrict__ mask,
    float* __restrict__ outS, float* __restrict__ ST)
{
    const int bid = blockIdx.x;
    const int b   = bid >> 8;
    const int xt  = ((bid >> 4) & 15) * 16;
    const int mt  = (bid & 15) * 16;
    const int t   = threadIdx.x;

    constexpr int PAD = 260;          // floats per LDS row (2-way conflicts only)
    __shared__ __align__(16) float s1[16 * PAD];
    __shared__ __align__(16) float s2[16 * PAD];
    __shared__ float stile[16 * 17];

    const float4* i14 = reinterpret_cast<const float4*>(i1) + (b * L + xt) * (D / 4);
    const float4* i24 = reinterpret_cast<const float4*>(i2) + (b * L + mt) * (D / 4);
    float4* s14 = reinterpret_cast<float4*>(s1);
    float4* s24 = reinterpret_cast<float4*>(s2);
#pragma unroll
    for (int k = 0; k < 4; ++k) {
        int idx = k * 256 + t;
        int r = idx >> 6, c = idx & 63;
        s14[r * (PAD / 4) + c] = i14[r * (D / 4) + c];
        s24[r * (PAD / 4) + c] = i24[r * (D / 4) + c];
    }
    __syncthreads();

    const int xl = t >> 4, ml = t & 15;
    const float4* a4 = s14 + xl * (PAD / 4);
    const float4* b4 = s24 + ml * (PAD / 4);
    const float4* w4 = reinterpret_cast<const float4*>(wst);  // uniform -> s_load
    float acc = 0.0f;
#pragma unroll 4
    for (int d4 = 0; d4 < D / 4; ++d4) {
        float4 a  = a4[d4];
        float4 bb = b4[d4];
        float4 w  = w4[d4];
        acc = fmaf(tanh_fast(a.x + bb.x), w.x, acc);
        acc = fmaf(tanh_fast(a.y + bb.y), w.y, acc);
        acc = fmaf(tanh_fast(a.z + bb.z), w.z, acc);
        acc = fmaf(tanh_fast(a.w + bb.w), w.w, acc);
    }
    const int xi = xt + xl, mi = mt + ml;
    outS[((b * L + xi) << 8) + mi] = (mask[b * L + mi] == 0) ? -1e30f : acc;

    stile[ml * 17 + xl] = acc;        // transpose tile in LDS
    __syncthreads();
    const int m2 = t >> 4, x2 = t & 15;
    ST[((b * L + mt + m2) << 8) + xt + x2] = stile[m2 * 17 + x2];
}

// ---------------------------------------------------------------------------
// Kernel 3 (fused both attentions): blocks [0,256): softmax(S1)@V1 -> out1,
// blocks [256,512): softmax(S2)@V2 -> out2.  4 rows/block, one wave per row,
// wave-local softmax (shfl only), then block-cooperative P@V.
// ---------------------------------------------------------------------------
__global__ __launch_bounds__(256) void attn_kernel(
    const float* __restrict__ S1, const float* __restrict__ V1, float* __restrict__ out1,
    const float* __restrict__ S2, const float* __restrict__ V2, float* __restrict__ out2)
{
    int bid = blockIdx.x;
    const float* S; const float* V; float* out;
    if (bid < NB * L / 4) { S = S1; V = V1; out = out1; }
    else                  { S = S2; V = V2; out = out2; bid -= NB * L / 4; }

    const int row0 = bid * 4;
    const int b    = row0 >> 8;       // 4-row group never straddles batches
    const int t    = threadIdx.x;
    const int w    = t >> 6, l = t & 63;

    __shared__ __align__(16) float p[4][L];
    __shared__ __align__(16) float4 part[4][4][64];

    // --- wave-local softmax: wave w owns row row0+w, lane l owns m=4l..4l+3
    {
        float4 sv = reinterpret_cast<const float4*>(S)[((row0 + w) << 6) + l];
        float m = fmaxf(fmaxf(sv.x, sv.y), fmaxf(sv.z, sv.w));
#pragma unroll
        for (int o = 32; o; o >>= 1) m = fmaxf(m, __shfl_xor(m, o));
        float e0 = fast_exp(sv.x - m), e1 = fast_exp(sv.y - m);
        float e2 = fast_exp(sv.z - m), e3 = fast_exp(sv.w - m);
        float s = (e0 + e1) + (e2 + e3);
#pragma unroll
        for (int o = 32; o; o >>= 1) s += __shfl_xor(s, o);
        float rs = fast_rcp(s);
        reinterpret_cast<float4*>(p[w])[l] = make_float4(e0 * rs, e1 * rs, e2 * rs, e3 * rs);
    }
    __syncthreads();

    // --- P @ V: wave w covers m in [64w, 64w+64), lane l owns d4=l
    const float4* V4 = reinterpret_cast<const float4*>(V) + (b * L) * (D / 4);
    float4 acc[4];
#pragma unroll
    for (int r = 0; r < 4; ++r) acc[r] = make_float4(0.f, 0.f, 0.f, 0.f);

#pragma unroll 4
    for (int k = 0; k < 64; ++k) {
        int mm = w * 64 + k;
        float4 v = V4[mm * (D / 4) + l];
#pragma unroll
        for (int r = 0; r < 4; ++r) {
            float pm = p[r][mm];      // LDS broadcast
            acc[r].x = fmaf(pm, v.x, acc[r].x);
            acc[r].y = fmaf(pm, v.y, acc[r].y);
            acc[r].z = fmaf(pm, v.z, acc[r].z);
            acc[r].w = fmaf(pm, v.w, acc[r].w);
        }
    }
#pragma unroll
    for (int r = 0; r < 4; ++r) part[r][w][l] = acc[r];
    __syncthreads();

    // --- reduce quarters: thread (r=w, d4=l)
    {
        float4 r0 = part[w][0][l], r1 = part[w][1][l];
        float4 r2 = part[w][2][l], r3 = part[w][3][l];
        float4 o;
        o.x = (r0.x + r1.x) + (r2.x + r3.x);
        o.y = (r0.y + r1.y) + (r2.y + r3.y);
        o.z = (r0.z + r1.z) + (r2.z + r3.z);
        o.w = (r0.w + r1.w) + (r2.w + r3.w);
        reinterpret_cast<float4*>(out)[((row0 + w) << 6) + l] = o;
    }
}

extern "C" void kernel_launch(void* const* d_in, const int* in_sizes, int n_in,
                              void* d_out, int out_size, void* d_ws, size_t ws_size,
                              hipStream_t stream)
{
    const float* x    = (const float*)d_in[0];  // [4,256,256]
    const float* mem  = (const float*)d_in[1];  // [4,256,256]
    const int*   mask = (const int*)  d_in[2];  // [4,256]
    const float* w1   = (const float*)d_in[3];  // [256,256]
    const float* b1   = (const float*)d_in[4];  // [256]
    const float* w2   = (const float*)d_in[5];  // [256,256]
    const float* wst  = (const float*)d_in[6];  // [256]

    float* out   = (float*)d_out;               // [4,256,256]
    float* Smask = out + NB * L * L;            // [4,256,256] (masked S, output 1)
    float* agg   = Smask + NB * L * L;          // [4,256,256] (agg_2_h, output 2)

    float* i1 = (float*)d_ws;                   // [4,256,256]
    float* i2 = i1 + NB * L * D;                // [4,256,256]
    float* ST = i2 + NB * L * D;                // [4,256,256] unmasked S^T

    constexpr int ROWS = 4;
    linear_kernel<ROWS><<<2 * (NB * L / ROWS), 256, 0, stream>>>(x, mem, w1, b1, w2, i1, i2);
    score_kernel<<<NB * (L / 16) * (L / 16), 256, 0, stream>>>(i1, i2, wst, mask, Smask, ST);
    attn_kernel<<<2 * (NB * L / 4), 256, 0, stream>>>(Smask, mem, out, ST, x, agg);
}

// Round 3
// 39.876 us; speedup vs baseline: 1.7331x; 1.2543x over previous
//
#include <hip/hip_runtime.h>

static constexpr int NB = 4;    // batch
static constexpr int L  = 256;  // Lx == Lm
static constexpr int D  = 256;

__device__ __forceinline__ float fast_rcp(float x) {
#if __has_builtin(__builtin_amdgcn_rcpf)
    return __builtin_amdgcn_rcpf(x);
#else
    return 1.0f / x;
#endif
}

__device__ __forceinline__ float fast_exp(float x) {
#if __has_builtin(__builtin_amdgcn_exp2f)
    return __builtin_amdgcn_exp2f(x * 1.4426950408889634f);
#else
    return __expf(x);
#endif
}

// tanh(y) = 1 - 2/(exp(2y)+1);  exp(2y) = exp2(y * 2*log2(e))
__device__ __forceinline__ float tanh_fast(float y) {
#if __has_builtin(__builtin_amdgcn_exp2f)
    float e = __builtin_amdgcn_exp2f(y * 2.8853900817779268f);
#else
    float e = __expf(2.0f * y);
#endif
    return fmaf(-2.0f, fast_rcp(e + 1.0f), 1.0f);
}

// ---------------------------------------------------------------------------
// Kernel 1 (v2): tiled GEMM for both linears, coalesced W access.
// Row space 0..1023 -> i1 = x@W1^T + b1 ; 1024..2047 -> i2 = mem@W2^T.
// Block = 32 rows x 32 cols, thread = 2x2 micro-tile. LDS tiles PAD=260.
// ---------------------------------------------------------------------------
__global__ __launch_bounds__(256) void linear_kernel(
    const float* __restrict__ x, const float* __restrict__ mem,
    const float* __restrict__ w1, const float* __restrict__ b1,
    const float* __restrict__ w2,
    float* __restrict__ i1, float* __restrict__ i2)
{
    const int bid = blockIdx.x;           // 512 blocks: 64 rowgroups x 8 colgroups
    const int rb  = (bid >> 3) * 32;      // 0..2047
    const int cb  = (bid & 7) * 32;
    const int which = rb >= 1024;
    const int rloc  = which ? rb - 1024 : rb;
    const float* src = which ? mem : x;
    const float* W   = which ? w2  : w1;
    float*       dst = which ? i2  : i1;

    constexpr int P4 = 65;                // float4 per LDS row (260 floats)
    __shared__ __align__(16) float4 xs4[32 * P4];
    __shared__ __align__(16) float4 ws4[32 * P4];

    const int t = threadIdx.x;
    const float4* src4 = reinterpret_cast<const float4*>(src) + rloc * 64;
    const float4* Wg4  = reinterpret_cast<const float4*>(W)   + cb   * 64;
#pragma unroll
    for (int k = 0; k < 8; ++k) {
        int idx = k * 256 + t;            // one full 1KB row per wave-instr
        int r = idx >> 6, c = idx & 63;
        xs4[r * P4 + c] = src4[r * 64 + c];
        ws4[r * P4 + c] = Wg4[r * 64 + c];
    }
    __syncthreads();

    const int rr = t >> 4, cc = t & 15;   // rows {rr, rr+16}, cols {cc, cc+16}
    const float4* a0p = xs4 + rr * P4;
    const float4* a1p = xs4 + (rr + 16) * P4;
    const float4* w0p = ws4 + cc * P4;
    const float4* w1p = ws4 + (cc + 16) * P4;
    float acc00 = 0.f, acc01 = 0.f, acc10 = 0.f, acc11 = 0.f;
#pragma unroll 4
    for (int d4 = 0; d4 < 64; ++d4) {
        float4 a0 = a0p[d4], a1 = a1p[d4];
        float4 w0 = w0p[d4], w1 = w1p[d4];
        acc00 = fmaf(a0.x, w0.x, acc00); acc00 = fmaf(a0.y, w0.y, acc00);
        acc00 = fmaf(a0.z, w0.z, acc00); acc00 = fmaf(a0.w, w0.w, acc00);
        acc01 = fmaf(a0.x, w1.x, acc01); acc01 = fmaf(a0.y, w1.y, acc01);
        acc01 = fmaf(a0.z, w1.z, acc01); acc01 = fmaf(a0.w, w1.w, acc01);
        acc10 = fmaf(a1.x, w0.x, acc10); acc10 = fmaf(a1.y, w0.y, acc10);
        acc10 = fmaf(a1.z, w0.z, acc10); acc10 = fmaf(a1.w, w0.w, acc10);
        acc11 = fmaf(a1.x, w1.x, acc11); acc11 = fmaf(a1.y, w1.y, acc11);
        acc11 = fmaf(a1.z, w1.z, acc11); acc11 = fmaf(a1.w, w1.w, acc11);
    }
    const float bias0 = which ? 0.f : b1[cb + cc];
    const float bias1 = which ? 0.f : b1[cb + cc + 16];
    dst[(rloc + rr)      * D + cb + cc]      = acc00 + bias0;
    dst[(rloc + rr)      * D + cb + cc + 16] = acc01 + bias1;
    dst[(rloc + rr + 16) * D + cb + cc]      = acc10 + bias0;
    dst[(rloc + rr + 16) * D + cb + cc + 16] = acc11 + bias1;
}

// ---------------------------------------------------------------------------
// Kernel 2: S[b,x,m] = sum_d tanh(i1[b,x,d] + i2[b,m,d]) * wst[d]
// 16x16 (x,m) tile per block; writes masked S to outS, unmasked S^T to ST.
// ---------------------------------------------------------------------------
__global__ __launch_bounds__(256) void score_kernel(
    const float* __restrict__ i1, const float* __restrict__ i2,
    const float* __restrict__ wst, const int* __restrict__ mask,
    float* __restrict__ outS, float* __restrict__ ST)
{
    const int bid = blockIdx.x;
    const int b   = bid >> 8;
    const int xt  = ((bid >> 4) & 15) * 16;
    const int mt  = (bid & 15) * 16;
    const int t   = threadIdx.x;

    constexpr int PAD = 260;          // floats per LDS row (2-way conflicts only)
    __shared__ __align__(16) float s1[16 * PAD];
    __shared__ __align__(16) float s2[16 * PAD];
    __shared__ float stile[16 * 17];

    const float4* i14 = reinterpret_cast<const float4*>(i1) + (b * L + xt) * (D / 4);
    const float4* i24 = reinterpret_cast<const float4*>(i2) + (b * L + mt) * (D / 4);
    float4* s14 = reinterpret_cast<float4*>(s1);
    float4* s24 = reinterpret_cast<float4*>(s2);
#pragma unroll
    for (int k = 0; k < 4; ++k) {
        int idx = k * 256 + t;
        int r = idx >> 6, c = idx & 63;
        s14[r * (PAD / 4) + c] = i14[r * (D / 4) + c];
        s24[r * (PAD / 4) + c] = i24[r * (D / 4) + c];
    }
    __syncthreads();

    const int xl = t >> 4, ml = t & 15;
    const float4* a4 = s14 + xl * (PAD / 4);
    const float4* b4 = s24 + ml * (PAD / 4);
    const float4* w4 = reinterpret_cast<const float4*>(wst);  // uniform -> s_load
    float acc = 0.0f;
#pragma unroll 4
    for (int d4 = 0; d4 < D / 4; ++d4) {
        float4 a  = a4[d4];
        float4 bb = b4[d4];
        float4 w  = w4[d4];
        acc = fmaf(tanh_fast(a.x + bb.x), w.x, acc);
        acc = fmaf(tanh_fast(a.y + bb.y), w.y, acc);
        acc = fmaf(tanh_fast(a.z + bb.z), w.z, acc);
        acc = fmaf(tanh_fast(a.w + bb.w), w.w, acc);
    }
    const int xi = xt + xl, mi = mt + ml;
    outS[((b * L + xi) << 8) + mi] = (mask[b * L + mi] == 0) ? -1e30f : acc;

    stile[ml * 17 + xl] = acc;        // transpose tile in LDS
    __syncthreads();
    const int m2 = t >> 4, x2 = t & 15;
    ST[((b * L + mt + m2) << 8) + xt + x2] = stile[m2 * 17 + x2];
}

// ---------------------------------------------------------------------------
// Kernel 3 (fused both attentions): blocks [0,256): softmax(S1)@V1 -> out1,
// blocks [256,512): softmax(S2)@V2 -> out2.  4 rows/block, one wave per row,
// wave-local softmax (shfl only), then block-cooperative P@V.
// ---------------------------------------------------------------------------
__global__ __launch_bounds__(256) void attn_kernel(
    const float* __restrict__ S1, const float* __restrict__ V1, float* __restrict__ out1,
    const float* __restrict__ S2, const float* __restrict__ V2, float* __restrict__ out2)
{
    int bid = blockIdx.x;
    const float* S; const float* V; float* out;
    if (bid < NB * L / 4) { S = S1; V = V1; out = out1; }
    else                  { S = S2; V = V2; out = out2; bid -= NB * L / 4; }

    const int row0 = bid * 4;
    const int b    = row0 >> 8;       // 4-row group never straddles batches
    const int t    = threadIdx.x;
    const int w    = t >> 6, l = t & 63;

    __shared__ __align__(16) float p[4][L];
    __shared__ __align__(16) float4 part[4][4][64];

    // --- wave-local softmax: wave w owns row row0+w, lane l owns m=4l..4l+3
    {
        float4 sv = reinterpret_cast<const float4*>(S)[((row0 + w) << 6) + l];
        float m = fmaxf(fmaxf(sv.x, sv.y), fmaxf(sv.z, sv.w));
#pragma unroll
        for (int o = 32; o; o >>= 1) m = fmaxf(m, __shfl_xor(m, o));
        float e0 = fast_exp(sv.x - m), e1 = fast_exp(sv.y - m);
        float e2 = fast_exp(sv.z - m), e3 = fast_exp(sv.w - m);
        float s = (e0 + e1) + (e2 + e3);
#pragma unroll
        for (int o = 32; o; o >>= 1) s += __shfl_xor(s, o);
        float rs = fast_rcp(s);
        reinterpret_cast<float4*>(p[w])[l] = make_float4(e0 * rs, e1 * rs, e2 * rs, e3 * rs);
    }
    __syncthreads();

    // --- P @ V: wave w covers m in [64w, 64w+64), lane l owns d4=l
    const float4* V4 = reinterpret_cast<const float4*>(V) + (b * L) * (D / 4);
    float4 acc[4];
#pragma unroll
    for (int r = 0; r < 4; ++r) acc[r] = make_float4(0.f, 0.f, 0.f, 0.f);

#pragma unroll 4
    for (int k = 0; k < 64; ++k) {
        int mm = w * 64 + k;
        float4 v = V4[mm * (D / 4) + l];
#pragma unroll
        for (int r = 0; r < 4; ++r) {
            float pm = p[r][mm];      // LDS broadcast
            acc[r].x = fmaf(pm, v.x, acc[r].x);
            acc[r].y = fmaf(pm, v.y, acc[r].y);
            acc[r].z = fmaf(pm, v.z, acc[r].z);
            acc[r].w = fmaf(pm, v.w, acc[r].w);
        }
    }
#pragma unroll
    for (int r = 0; r < 4; ++r) part[r][w][l] = acc[r];
    __syncthreads();

    // --- reduce quarters: thread (r=w, d4=l)
    {
        float4 r0 = part[w][0][l], r1 = part[w][1][l];
        float4 r2 = part[w][2][l], r3 = part[w][3][l];
        float4 o;
        o.x = (r0.x + r1.x) + (r2.x + r3.x);
        o.y = (r0.y + r1.y) + (r2.y + r3.y);
        o.z = (r0.z + r1.z) + (r2.z + r3.z);
        o.w = (r0.w + r1.w) + (r2.w + r3.w);
        reinterpret_cast<float4*>(out)[((row0 + w) << 6) + l] = o;
    }
}

extern "C" void kernel_launch(void* const* d_in, const int* in_sizes, int n_in,
                              void* d_out, int out_size, void* d_ws, size_t ws_size,
                              hipStream_t stream)
{
    const float* x    = (const float*)d_in[0];  // [4,256,256]
    const float* mem  = (const float*)d_in[1];  // [4,256,256]
    const int*   mask = (const int*)  d_in[2];  // [4,256]
    const float* w1   = (const float*)d_in[3];  // [256,256]
    const float* b1   = (const float*)d_in[4];  // [256]
    const float* w2   = (const float*)d_in[5];  // [256,256]
    const float* wst  = (const float*)d_in[6];  // [256]

    float* out   = (float*)d_out;               // [4,256,256]
    float* Smask = out + NB * L * L;            // [4,256,256] (masked S, output 1)
    float* agg   = Smask + NB * L * L;          // [4,256,256] (agg_2_h, output 2)

    float* i1 = (float*)d_ws;                   // [4,256,256]
    float* i2 = i1 + NB * L * D;                // [4,256,256]
    float* ST = i2 + NB * L * D;                // [4,256,256] unmasked S^T

    linear_kernel<<<512, 256, 0, stream>>>(x, mem, w1, b1, w2, i1, i2);
    score_kernel<<<NB * (L / 16) * (L / 16), 256, 0, stream>>>(i1, i2, wst, mask, Smask, ST);
    attn_kernel<<<2 * (NB * L / 4), 256, 0, stream>>>(Smask, mem, out, ST, x, agg);
}

// Round 4
// 38.840 us; speedup vs baseline: 1.7794x; 1.0267x over previous
//
#include <hip/hip_runtime.h>

static constexpr int NB = 4;    // batch
static constexpr int L  = 256;  // Lx == Lm
static constexpr int D  = 256;

__device__ __forceinline__ float fast_rcp(float x) {
#if __has_builtin(__builtin_amdgcn_rcpf)
    return __builtin_amdgcn_rcpf(x);
#else
    return 1.0f / x;
#endif
}

__device__ __forceinline__ float fast_exp(float x) {   // e^x
#if __has_builtin(__builtin_amdgcn_exp2f)
    return __builtin_amdgcn_exp2f(x * 1.4426950408889634f);
#else
    return __expf(x);
#endif
}

__device__ __forceinline__ float exp_2x(float x) {     // e^(2x)
#if __has_builtin(__builtin_amdgcn_exp2f)
    return __builtin_amdgcn_exp2f(x * 2.8853900817779268f);
#else
    return __expf(2.0f * x);
#endif
}

// tanh(a+b) given e = exp(2a)*exp(2b):  tanh = 1 - 2/(e+1)
__device__ __forceinline__ float tanh_from_e(float e) {
    return fmaf(-2.0f, fast_rcp(e + 1.0f), 1.0f);
}

// ---------------------------------------------------------------------------
// Kernel 1: tiled GEMM for both linears; epilogue writes E = exp(2*(row@W^T+b))
// Row space 0..1023 -> E1 (from x,W1,b1); 1024..2047 -> E2 (from mem,W2).
// Block = 32x32 tile, thread = 2x2 micro-tile. LDS rows PAD=260 floats.
// ---------------------------------------------------------------------------
__global__ __launch_bounds__(256) void linear_kernel(
    const float* __restrict__ x, const float* __restrict__ mem,
    const float* __restrict__ w1, const float* __restrict__ b1,
    const float* __restrict__ w2,
    float* __restrict__ E1, float* __restrict__ E2)
{
    const int bid = blockIdx.x;           // 512 blocks: 64 rowgroups x 8 colgroups
    const int rb  = (bid >> 3) * 32;      // 0..2047
    const int cb  = (bid & 7) * 32;
    const int which = rb >= 1024;
    const int rloc  = which ? rb - 1024 : rb;
    const float* src = which ? mem : x;
    const float* W   = which ? w2  : w1;
    float*       dst = which ? E2  : E1;

    constexpr int P4 = 65;                // float4 per LDS row (260 floats)
    __shared__ __align__(16) float4 xs4[32 * P4];
    __shared__ __align__(16) float4 ws4[32 * P4];

    const int t = threadIdx.x;
    const float4* src4 = reinterpret_cast<const float4*>(src) + rloc * 64;
    const float4* Wg4  = reinterpret_cast<const float4*>(W)   + cb   * 64;
#pragma unroll
    for (int k = 0; k < 8; ++k) {
        int idx = k * 256 + t;            // one full 1KB row per wave-instr
        int r = idx >> 6, c = idx & 63;
        xs4[r * P4 + c] = src4[r * 64 + c];
        ws4[r * P4 + c] = Wg4[r * 64 + c];
    }
    __syncthreads();

    const int rr = t >> 4, cc = t & 15;   // rows {rr, rr+16}, cols {cc, cc+16}
    const float4* a0p = xs4 + rr * P4;
    const float4* a1p = xs4 + (rr + 16) * P4;
    const float4* w0p = ws4 + cc * P4;
    const float4* w1p = ws4 + (cc + 16) * P4;
    float acc00 = 0.f, acc01 = 0.f, acc10 = 0.f, acc11 = 0.f;
#pragma unroll 4
    for (int d4 = 0; d4 < 64; ++d4) {
        float4 a0 = a0p[d4], a1 = a1p[d4];
        float4 w0 = w0p[d4], w1 = w1p[d4];
        acc00 = fmaf(a0.x, w0.x, acc00); acc00 = fmaf(a0.y, w0.y, acc00);
        acc00 = fmaf(a0.z, w0.z, acc00); acc00 = fmaf(a0.w, w0.w, acc00);
        acc01 = fmaf(a0.x, w1.x, acc01); acc01 = fmaf(a0.y, w1.y, acc01);
        acc01 = fmaf(a0.z, w1.z, acc01); acc01 = fmaf(a0.w, w1.w, acc01);
        acc10 = fmaf(a1.x, w0.x, acc10); acc10 = fmaf(a1.y, w0.y, acc10);
        acc10 = fmaf(a1.z, w0.z, acc10); acc10 = fmaf(a1.w, w0.w, acc10);
        acc11 = fmaf(a1.x, w1.x, acc11); acc11 = fmaf(a1.y, w1.y, acc11);
        acc11 = fmaf(a1.z, w1.z, acc11); acc11 = fmaf(a1.w, w1.w, acc11);
    }
    const float bias0 = which ? 0.f : b1[cb + cc];
    const float bias1 = which ? 0.f : b1[cb + cc + 16];
    dst[(rloc + rr)      * D + cb + cc]      = exp_2x(acc00 + bias0);
    dst[(rloc + rr)      * D + cb + cc + 16] = exp_2x(acc01 + bias1);
    dst[(rloc + rr + 16) * D + cb + cc]      = exp_2x(acc10 + bias0);
    dst[(rloc + rr + 16) * D + cb + cc + 16] = exp_2x(acc11 + bias1);
}

// ---------------------------------------------------------------------------
// Kernel 2: S[b,x,m] = sum_d tanh(i1+i2)*w  via  e = E1[x,d]*E2[m,d]
// 32x32 (x,m) tile per block, 2x2 micro-tile per thread.
// Writes masked S to outS, unmasked S^T to ST.
// ---------------------------------------------------------------------------
__global__ __launch_bounds__(256) void score_kernel(
    const float* __restrict__ E1, const float* __restrict__ E2,
    const float* __restrict__ wst, const int* __restrict__ mask,
    float* __restrict__ outS, float* __restrict__ ST)
{
    const int bid = blockIdx.x;           // 256 blocks: b(4) x xt(8) x mt(8)
    const int b   = bid >> 6;
    const int xt  = ((bid >> 3) & 7) * 32;
    const int mt  = (bid & 7) * 32;
    const int t   = threadIdx.x;

    constexpr int P4 = 65;                // float4 per LDS row
    __shared__ __align__(16) float4 s1[32 * P4];
    __shared__ __align__(16) float4 s2[32 * P4];
    __shared__ float stile[32 * 33];

    const float4* e14 = reinterpret_cast<const float4*>(E1) + (b * L + xt) * 64;
    const float4* e24 = reinterpret_cast<const float4*>(E2) + (b * L + mt) * 64;
#pragma unroll
    for (int k = 0; k < 8; ++k) {
        int idx = k * 256 + t;
        int r = idx >> 6, c = idx & 63;
        s1[r * P4 + c] = e14[r * 64 + c];
        s2[r * P4 + c] = e24[r * 64 + c];
    }
    __syncthreads();

    const int rr = t >> 4, cc = t & 15;   // x-rows {rr, rr+16}, m-rows {cc, cc+16}
    const float4* a0p = s1 + rr * P4;
    const float4* a1p = s1 + (rr + 16) * P4;
    const float4* b0p = s2 + cc * P4;
    const float4* b1p = s2 + (cc + 16) * P4;
    const float4* w4  = reinterpret_cast<const float4*>(wst);  // uniform -> s_load
    float acc00 = 0.f, acc01 = 0.f, acc10 = 0.f, acc11 = 0.f;
#pragma unroll 4
    for (int d4 = 0; d4 < 64; ++d4) {
        float4 a0 = a0p[d4], a1 = a1p[d4];
        float4 b0 = b0p[d4], b1 = b1p[d4];
        float4 w  = w4[d4];
        acc00 = fmaf(tanh_from_e(a0.x * b0.x), w.x, acc00);
        acc00 = fmaf(tanh_from_e(a0.y * b0.y), w.y, acc00);
        acc00 = fmaf(tanh_from_e(a0.z * b0.z), w.z, acc00);
        acc00 = fmaf(tanh_from_e(a0.w * b0.w), w.w, acc00);
        acc01 = fmaf(tanh_from_e(a0.x * b1.x), w.x, acc01);
        acc01 = fmaf(tanh_from_e(a0.y * b1.y), w.y, acc01);
        acc01 = fmaf(tanh_from_e(a0.z * b1.z), w.z, acc01);
        acc01 = fmaf(tanh_from_e(a0.w * b1.w), w.w, acc01);
        acc10 = fmaf(tanh_from_e(a1.x * b0.x), w.x, acc10);
        acc10 = fmaf(tanh_from_e(a1.y * b0.y), w.y, acc10);
        acc10 = fmaf(tanh_from_e(a1.z * b0.z), w.z, acc10);
        acc10 = fmaf(tanh_from_e(a1.w * b0.w), w.w, acc10);
        acc11 = fmaf(tanh_from_e(a1.x * b1.x), w.x, acc11);
        acc11 = fmaf(tanh_from_e(a1.y * b1.y), w.y, acc11);
        acc11 = fmaf(tanh_from_e(a1.z * b1.z), w.z, acc11);
        acc11 = fmaf(tanh_from_e(a1.w * b1.w), w.w, acc11);
    }

    const int m0 = mt + cc, m1 = mt + cc + 16;
    const int x0 = xt + rr, x1 = xt + rr + 16;
    const bool k0 = (mask[b * L + m0] == 0), k1 = (mask[b * L + m1] == 0);
    outS[((b * L + x0) << 8) + m0] = k0 ? -1e30f : acc00;
    outS[((b * L + x0) << 8) + m1] = k1 ? -1e30f : acc01;
    outS[((b * L + x1) << 8) + m0] = k0 ? -1e30f : acc10;
    outS[((b * L + x1) << 8) + m1] = k1 ? -1e30f : acc11;

    stile[cc        * 33 + rr]      = acc00;   // transpose tile in LDS
    stile[(cc + 16) * 33 + rr]      = acc01;
    stile[cc        * 33 + rr + 16] = acc10;
    stile[(cc + 16) * 33 + rr + 16] = acc11;
    __syncthreads();
#pragma unroll
    for (int k = 0; k < 4; ++k) {
        int idx = k * 256 + t;
        int mr = idx >> 5, xc = idx & 31;
        ST[((b * L + mt + mr) << 8) + xt + xc] = stile[mr * 33 + xc];
    }
}

// ---------------------------------------------------------------------------
// Kernel 3 (fused both attentions): blocks [0,128): softmax(S1)@V1 -> out1,
// [128,256): softmax(S2)@V2 -> out2.  8 rows/block, wave-local softmax,
// chunked float4 p-reads in P@V.
// ---------------------------------------------------------------------------
__global__ __launch_bounds__(256) void attn_kernel(
    const float* __restrict__ S1, const float* __restrict__ V1, float* __restrict__ out1,
    const float* __restrict__ S2, const float* __restrict__ V2, float* __restrict__ out2)
{
    int bid = blockIdx.x;
    const float* S; const float* V; float* out;
    if (bid < NB * L / 8) { S = S1; V = V1; out = out1; }
    else                  { S = S2; V = V2; out = out2; bid -= NB * L / 8; }

    const int row0 = bid * 8;
    const int b    = row0 >> 8;       // 8-row group never straddles batches
    const int t    = threadIdx.x;
    const int w    = t >> 6, l = t & 63;

    __shared__ __align__(16) float p[8][L];
    __shared__ __align__(16) float4 part[8][4][64];

    // --- wave-local softmax: wave w owns rows {w, w+4}, lane l owns m=4l..4l+3
#pragma unroll
    for (int rr = w; rr < 8; rr += 4) {
        float4 sv = reinterpret_cast<const float4*>(S)[((row0 + rr) << 6) + l];
        float m = fmaxf(fmaxf(sv.x, sv.y), fmaxf(sv.z, sv.w));
#pragma unroll
        for (int o = 32; o; o >>= 1) m = fmaxf(m, __shfl_xor(m, o));
        float e0 = fast_exp(sv.x - m), e1 = fast_exp(sv.y - m);
        float e2 = fast_exp(sv.z - m), e3 = fast_exp(sv.w - m);
        float s = (e0 + e1) + (e2 + e3);
#pragma unroll
        for (int o = 32; o; o >>= 1) s += __shfl_xor(s, o);
        float rs = fast_rcp(s);
        reinterpret_cast<float4*>(p[rr])[l] = make_float4(e0 * rs, e1 * rs, e2 * rs, e3 * rs);
    }
    __syncthreads();

    // --- P @ V: wave w covers m in [64w, 64w+64), lane l owns d4=l
    const float4* V4 = reinterpret_cast<const float4*>(V) + (b * L) * 64;
    float4 acc[8];
#pragma unroll
    for (int r = 0; r < 8; ++r) acc[r] = make_float4(0.f, 0.f, 0.f, 0.f);

#pragma unroll 2
    for (int k4 = 0; k4 < 16; ++k4) {
        const int m0 = w * 64 + k4 * 4;
        float4 v0 = V4[(m0 + 0) * 64 + l];
        float4 v1 = V4[(m0 + 1) * 64 + l];
        float4 v2 = V4[(m0 + 2) * 64 + l];
        float4 v3 = V4[(m0 + 3) * 64 + l];
#pragma unroll
        for (int r = 0; r < 8; ++r) {
            float4 pr = *reinterpret_cast<const float4*>(&p[r][m0]);  // broadcast b128
            acc[r].x = fmaf(pr.x, v0.x, acc[r].x); acc[r].y = fmaf(pr.x, v0.y, acc[r].y);
            acc[r].z = fmaf(pr.x, v0.z, acc[r].z); acc[r].w = fmaf(pr.x, v0.w, acc[r].w);
            acc[r].x = fmaf(pr.y, v1.x, acc[r].x); acc[r].y = fmaf(pr.y, v1.y, acc[r].y);
            acc[r].z = fmaf(pr.y, v1.z, acc[r].z); acc[r].w = fmaf(pr.y, v1.w, acc[r].w);
            acc[r].x = fmaf(pr.z, v2.x, acc[r].x); acc[r].y = fmaf(pr.z, v2.y, acc[r].y);
            acc[r].z = fmaf(pr.z, v2.z, acc[r].z); acc[r].w = fmaf(pr.z, v2.w, acc[r].w);
            acc[r].x = fmaf(pr.w, v3.x, acc[r].x); acc[r].y = fmaf(pr.w, v3.y, acc[r].y);
            acc[r].z = fmaf(pr.w, v3.z, acc[r].z); acc[r].w = fmaf(pr.w, v3.w, acc[r].w);
        }
    }
#pragma unroll
    for (int r = 0; r < 8; ++r) part[r][w][l] = acc[r];
    __syncthreads();

    // --- reduce quarters: wave w handles rows {w, w+4}
#pragma unroll
    for (int rr = w; rr < 8; rr += 4) {
        float4 r0 = part[rr][0][l], r1 = part[rr][1][l];
        float4 r2 = part[rr][2][l], r3 = part[rr][3][l];
        float4 o;
        o.x = (r0.x + r1.x) + (r2.x + r3.x);
        o.y = (r0.y + r1.y) + (r2.y + r3.y);
        o.z = (r0.z + r1.z) + (r2.z + r3.z);
        o.w = (r0.w + r1.w) + (r2.w + r3.w);
        reinterpret_cast<float4*>(out)[((row0 + rr) << 6) + l] = o;
    }
}

extern "C" void kernel_launch(void* const* d_in, const int* in_sizes, int n_in,
                              void* d_out, int out_size, void* d_ws, size_t ws_size,
                              hipStream_t stream)
{
    const float* x    = (const float*)d_in[0];  // [4,256,256]
    const float* mem  = (const float*)d_in[1];  // [4,256,256]
    const int*   mask = (const int*)  d_in[2];  // [4,256]
    const float* w1   = (const float*)d_in[3];  // [256,256]
    const float* b1   = (const float*)d_in[4];  // [256]
    const float* w2   = (const float*)d_in[5];  // [256,256]
    const float* wst  = (const float*)d_in[6];  // [256]

    float* out   = (float*)d_out;               // [4,256,256]
    float* Smask = out + NB * L * L;            // [4,256,256] (masked S, output 1)
    float* agg   = Smask + NB * L * L;          // [4,256,256] (agg_2_h, output 2)

    float* E1 = (float*)d_ws;                   // [4,256,256] exp(2*i1)
    float* E2 = E1 + NB * L * D;                // [4,256,256] exp(2*i2)
    float* ST = E2 + NB * L * D;                // [4,256,256] unmasked S^T

    linear_kernel<<<512, 256, 0, stream>>>(x, mem, w1, b1, w2, E1, E2);
    score_kernel<<<NB * (L / 32) * (L / 32), 256, 0, stream>>>(E1, E2, wst, mask, Smask, ST);
    attn_kernel<<<2 * (NB * L / 8), 256, 0, stream>>>(Smask, mem, out, ST, x, agg);
}